// Round 1
// baseline (6884.658 us; speedup 1.0000x reference)
//
#include <hip/hip_runtime.h>

typedef unsigned short US;
typedef unsigned int   UI;
typedef short  short8 __attribute__((ext_vector_type(8)));
typedef US     u16x8  __attribute__((ext_vector_type(8)));
typedef float  f32x4  __attribute__((ext_vector_type(4)));

#define DEVI __device__ __forceinline__

DEVI float bf2f(US u){ UI i = ((UI)u) << 16; float f; __builtin_memcpy(&f, &i, 4); return f; }
DEVI US f2bf(float x){ UI i; __builtin_memcpy(&i, &x, 4); UI r = (i + 0x7FFFu + ((i >> 16) & 1u)) >> 16; return (US)r; }
DEVI float gelu_f(float x){ return 0.5f * x * (1.0f + erff(x * 0.70710678118654752f)); }
DEVI UI encf(float f){ UI u; __builtin_memcpy(&u, &f, 4); return (u & 0x80000000u) ? ~u : (u | 0x80000000u); }
DEVI float decf(UI u){ UI b = (u & 0x80000000u) ? (u ^ 0x80000000u) : ~u; float f; __builtin_memcpy(&f, &b, 4); return f; }

// ---------------------------------------------------------------------------
// Generic bf16 MFMA GEMM:  C[M,OUT] = epilogue( A[M,K] @ W[OUT,K]^T )
// BM=128, BK=64, 256 threads (4 waves).
// BN=128: waves 2x2, each 64x64 (MR=4,NR=4). BN=64: waves 4x1, each 32x64 (MR=2,NR=4).
// Epilogue: +bias (split lo/hi for stacked weights), +pre (bf16), act (0 none,
// 1 gelu [optionally only cols<128], 2 relu), +post (bf16), store bf16.
// SUM8: act=gelu then sum groups of 8 consecutive rows (point-set sum), store [M/8, OUT].
// ---------------------------------------------------------------------------
template<int K, int BN, int ACT, bool ACTLO, bool AF32, bool PRE, bool POST, bool SUM8>
__global__ __launch_bounds__(256, 2)
void gemm_k(const void* __restrict__ Ap, int lda, int M,
            const US* __restrict__ W,
            const float* __restrict__ bias0, const float* __restrict__ bias1,
            const US* __restrict__ pre, int ldpre,
            const US* __restrict__ post, int ldpost,
            US* __restrict__ C, int ldc)
{
    constexpr int BM = 128, BK = 64;
    __shared__ __align__(16) US As[BM * BK];
    __shared__ __align__(16) US Bs[BN * BK];

    const int tid  = threadIdx.x;
    const int lane = tid & 63;
    const int w    = tid >> 6;

    constexpr int MR = (BN == 128) ? 4 : 2;
    constexpr int NR = 4;
    const int rb = (BN == 128) ? (w >> 1) * 64 : w * 32;
    const int cb = (BN == 128) ? (w & 1) * 64 : 0;

    f32x4 acc[MR][NR];
    #pragma unroll
    for (int m = 0; m < MR; ++m)
        #pragma unroll
        for (int n = 0; n < NR; ++n)
            acc[m][n] = (f32x4){0.f, 0.f, 0.f, 0.f};

    const int  n0    = blockIdx.y * BN;
    const long grow0 = (long)blockIdx.x * BM;

    const int  arow  = tid >> 1;
    const int  acol  = (tid & 1) * 32;
    const long agrow = grow0 + arow;
    const bool rowok = agrow < (long)M;

    int brow, bcol, bchunks;
    if (BN == 128) { brow = tid >> 1; bcol = (tid & 1) * 32; bchunks = 4; }
    else           { brow = tid >> 2; bcol = (tid & 3) * 16; bchunks = 2; }

#define SWZ(r, c) ((((r) * BK) + (c)) ^ (((r) & 7) << 3))

    for (int k0 = 0; k0 < K; k0 += BK) {
        // ---- stage A tile (convert f32->bf16 on the fly if needed) ----
        if (AF32) {
            const float* Af = (const float*)Ap + (size_t)(rowok ? agrow : 0) * lda + k0 + acol;
            #pragma unroll
            for (int j = 0; j < 4; ++j) {
                float4 x0 = {0, 0, 0, 0}, x1 = {0, 0, 0, 0};
                if (rowok) { x0 = *(const float4*)(Af + 8 * j); x1 = *(const float4*)(Af + 8 * j + 4); }
                u16x8 v;
                v[0] = f2bf(x0.x); v[1] = f2bf(x0.y); v[2] = f2bf(x0.z); v[3] = f2bf(x0.w);
                v[4] = f2bf(x1.x); v[5] = f2bf(x1.y); v[6] = f2bf(x1.z); v[7] = f2bf(x1.w);
                *(u16x8*)&As[SWZ(arow, acol + 8 * j)] = v;
            }
        } else {
            const US* Ab = (const US*)Ap + (size_t)(rowok ? agrow : 0) * lda + k0 + acol;
            #pragma unroll
            for (int j = 0; j < 4; ++j) {
                u16x8 v = {0, 0, 0, 0, 0, 0, 0, 0};
                if (rowok) v = *(const u16x8*)(Ab + 8 * j);
                *(u16x8*)&As[SWZ(arow, acol + 8 * j)] = v;
            }
        }
        // ---- stage B tile (weights, bf16, L2-hot) ----
        {
            const US* Wp2 = W + (size_t)(n0 + brow) * K + k0 + bcol;
            #pragma unroll
            for (int j = 0; j < bchunks; ++j)
                *(u16x8*)&Bs[SWZ(brow, bcol + 8 * j)] = *(const u16x8*)(Wp2 + 8 * j);
        }
        __syncthreads();

        #pragma unroll
        for (int sub = 0; sub < 2; ++sub) {
            short8 a[MR], b[NR];
            const int kk = sub * 32 + ((lane >> 4) << 3);
            #pragma unroll
            for (int m = 0; m < MR; ++m) a[m] = *(const short8*)&As[SWZ(rb + m * 16 + (lane & 15), kk)];
            #pragma unroll
            for (int n = 0; n < NR; ++n) b[n] = *(const short8*)&Bs[SWZ(cb + n * 16 + (lane & 15), kk)];
            #pragma unroll
            for (int m = 0; m < MR; ++m)
                #pragma unroll
                for (int n = 0; n < NR; ++n)
                    acc[m][n] = __builtin_amdgcn_mfma_f32_16x16x32_bf16(a[m], b[n], acc[m][n], 0, 0, 0);
        }
        __syncthreads();
    }
#undef SWZ

    const int colBase = n0 + cb;
    if (!SUM8) {
        #pragma unroll
        for (int m = 0; m < MR; ++m) {
            const long growE = grow0 + rb + m * 16 + ((lane >> 4) << 2);
            #pragma unroll
            for (int n = 0; n < NR; ++n) {
                const int colg = colBase + n * 16 + (lane & 15);
                float bv = 0.f;
                if (bias0) bv = (bias1 && colg >= 128) ? bias1[colg - 128] : bias0[colg];
                #pragma unroll
                for (int r = 0; r < 4; ++r) {
                    const long row = growE + r;
                    if (row < (long)M) {
                        float v = acc[m][n][r] + bv;
                        if (PRE)  v += bf2f(pre[(size_t)row * ldpre + colg]);
                        if (ACT == 1) { if (!ACTLO || colg < 128) v = gelu_f(v); }
                        else if (ACT == 2) { v = fmaxf(v, 0.f); }
                        if (POST) v += bf2f(post[(size_t)row * ldpost + colg]);
                        C[(size_t)row * ldc + colg] = f2bf(v);
                    }
                }
            }
        }
    } else {
        // sum of gelu over 8 consecutive rows (K-points of one node)
        #pragma unroll
        for (int m = 0; m < MR; ++m) {
            const int nodeBase = (int)((grow0 + rb + m * 16) >> 3);
            #pragma unroll
            for (int n = 0; n < NR; ++n) {
                const int colg = colBase + n * 16 + (lane & 15);
                const float bv = bias0 ? bias0[colg] : 0.f;
                float s = 0.f;
                #pragma unroll
                for (int r = 0; r < 4; ++r) s += gelu_f(acc[m][n][r] + bv);
                s += __shfl_xor(s, 16);
                if (((lane >> 4) & 1) == 0) {
                    const int node = nodeBase + (lane >> 5);
                    if (node < (M >> 3)) C[(size_t)node * ldc + colg] = f2bf(s);
                }
            }
        }
    }
}

// ---------------------------------------------------------------------------
// Weight prep: f32 -> bf16, with in/proj pairs stacked into one matrix.
// ---------------------------------------------------------------------------
struct WSeg { const float* src; int dst; int n; };
struct WPrm { WSeg s[20]; };

__global__ void prep_w(WPrm p, US* __restrict__ wb)
{
    WSeg sg = p.s[blockIdx.x];
    for (int i = threadIdx.x; i < sg.n; i += 256) wb[sg.dst + i] = f2bf(sg.src[i]);
}

// ---------------------------------------------------------------------------
// CSR build (incoming edges per dst node)
// ---------------------------------------------------------------------------
__global__ void count_k(const int* __restrict__ dst, int* __restrict__ cnt, int E)
{
    int e = blockIdx.x * 256 + threadIdx.x;
    if (e < E) atomicAdd(&cnt[dst[e]], 1);
}

__global__ void scan_csr(const int* __restrict__ cnt, int n, int* __restrict__ indp, int* __restrict__ curs)
{
    __shared__ int wsum[16];
    __shared__ int carry_s;
    const int tid = threadIdx.x, lane = tid & 63, w = tid >> 6;
    if (tid == 0) carry_s = 0;
    __syncthreads();
    for (int base = 0; base < n; base += 1024) {
        const int i = base + tid;
        const int v = (i < n) ? cnt[i] : 0;
        int s = v;
        #pragma unroll
        for (int o = 1; o < 64; o <<= 1) { int t = __shfl_up(s, o); if (lane >= o) s += t; }
        if (lane == 63) wsum[w] = s;
        __syncthreads();
        if (w == 0 && lane < 16) {
            int ws2 = wsum[lane];
            #pragma unroll
            for (int o = 1; o < 16; o <<= 1) { int t = __shfl_up(ws2, o); if (lane >= o) ws2 += t; }
            wsum[lane] = ws2;
        }
        __syncthreads();
        const int carry = carry_s;
        const int woff  = (w == 0) ? 0 : wsum[w - 1];
        if (i < n) { const int excl = carry + woff + s - v; indp[i] = excl; curs[i] = excl; }
        __syncthreads();
        if (tid == 0) carry_s = carry + wsum[15];
        __syncthreads();
    }
    if (threadIdx.x == 0) indp[n] = carry_s;
}

__global__ void fill_k(const int* __restrict__ src, const int* __restrict__ dst,
                       int* __restrict__ curs, int* __restrict__ esrc, int E)
{
    int e = blockIdx.x * 256 + threadIdx.x;
    if (e < E) { int p = atomicAdd(&curs[dst[e]], 1); esrc[p] = src[e]; }
}

// mean-aggregate incoming neighbors; one wave per node, lane = feature (C=64)
__global__ void sage_agg(const US* __restrict__ z, const int* __restrict__ indp,
                         const int* __restrict__ esrc, US* __restrict__ agg, int n)
{
    const int w = blockIdx.x * 4 + (threadIdx.x >> 6);
    const int lane = threadIdx.x & 63;
    if (w >= n) return;
    const int beg = indp[w], end = indp[w + 1];
    float acc = 0.f;
    for (int j = beg; j < end; ++j) {
        const int s = esrc[j];
        acc += bf2f(z[(size_t)s * 64 + lane]);
    }
    const float d = (float)(end - beg);
    agg[(size_t)w * 64 + lane] = f2bf(acc / fmaxf(d, 1.0f));
}

// segment max over sorted batch ids (wave handles a run of nodes, lane = feature)
__global__ void segmax_k(const US* __restrict__ z, const int* __restrict__ batch,
                         UI* __restrict__ enc, int n, int per)
{
    const int w = blockIdx.x * 4 + (threadIdx.x >> 6);
    const int lane = threadIdx.x & 63;
    const int start = w * per;
    if (start >= n) return;
    const int end = (start + per < n) ? start + per : n;
    int g = batch[start];
    float m = -3.0e38f;
    for (int i = start; i < end; ++i) {
        const int b = batch[i];
        if (b != g) { atomicMax(&enc[(size_t)g * 64 + lane], encf(m)); g = b; m = -3.0e38f; }
        m = fmaxf(m, bf2f(z[(size_t)i * 64 + lane]));
    }
    atomicMax(&enc[(size_t)g * 64 + lane], encf(m));
}

__global__ void decode_ge(const UI* __restrict__ enc, US* __restrict__ geb)
{
    const int i = blockIdx.x * 256 + threadIdx.x;
    if (i < 4096) geb[i] = f2bf(decf(enc[i]));
}

// build xy (f32, into d_out) and yx (f32, scratch); one wave per query row
__global__ void build_q(const int* __restrict__ sq, const int* __restrict__ dq,
                        const int* __restrict__ batch, const US* __restrict__ z,
                        const US* __restrict__ geb,
                        float* __restrict__ xy, float* __restrict__ yx, int cq)
{
    const int w = blockIdx.x * 4 + (threadIdx.x >> 6);
    const int lane = threadIdx.x & 63;
    if (w >= cq) return;
    const int s = sq[w], d = dq[w];
    const int g = batch[s];
    const float zs = bf2f(z[(size_t)s * 64 + lane]);
    const float zd = bf2f(z[(size_t)d * 64 + lane]);
    const float ge = bf2f(geb[(size_t)g * 64 + lane]);
    float* xr = xy + (size_t)w * 192;
    float* yr = yx + (size_t)w * 192;
    xr[lane] = zs; xr[64 + lane] = zd; xr[128 + lane] = ge;
    yr[lane] = zd; yr[64 + lane] = zs; yr[128 + lane] = ge;
}

// final head projection to scalar: out[q] = U2[q,:] . W + b ; one wave per row
__global__ void head_dot(const US* __restrict__ U, const float* __restrict__ Wf,
                         const float* __restrict__ bp, float* __restrict__ o, int cq)
{
    const int w = blockIdx.x * 4 + (threadIdx.x >> 6);
    const int lane = threadIdx.x & 63;
    if (w >= cq) return;
    const US* u = U + (size_t)w * 128;
    float a = bf2f(u[lane]) * Wf[lane] + bf2f(u[64 + lane]) * Wf[64 + lane];
    #pragma unroll
    for (int o2 = 32; o2 > 0; o2 >>= 1) a += __shfl_xor(a, o2);
    if (lane == 0) o[w] = a + bp[0];
}

__global__ void copy_bf2f(const US* __restrict__ z, float* __restrict__ o, long n)
{
    long i = (long)blockIdx.x * blockDim.x + threadIdx.x;
    const long stride = (long)gridDim.x * blockDim.x;
    for (; i < n; i += stride) o[i] = bf2f(z[i]);
}

static inline int imin(int a, int b) { return a < b ? a : b; }

// ---------------------------------------------------------------------------
extern "C" void kernel_launch(void* const* d_in, const int* in_sizes, int n_in,
                              void* d_out, int out_size, void* d_ws, size_t ws_size,
                              hipStream_t stream)
{
    (void)in_sizes; (void)n_in; (void)out_size;

    const float* x      = (const float*)d_in[0];
    const int*   batch  = (const int*)d_in[1];
    const int*   eidx   = (const int*)d_in[2];
    const int*   srcq   = (const int*)d_in[3];
    const int*   dstq   = (const int*)d_in[4];
    const float* em_in_W   = (const float*)d_in[5];
    const float* em_in_b   = (const float*)d_in[6];
    const float* em_hid_W  = (const float*)d_in[7];
    const float* em_hid_b  = (const float*)d_in[8];
    const float* em_out_W  = (const float*)d_in[9];
    const float* em_out_b  = (const float*)d_in[10];
    const float* em_proj_W = (const float*)d_in[11];
    const float* em_proj_b = (const float*)d_in[12];
    const float* rho_in_W  = (const float*)d_in[13];
    const float* rho_in_b  = (const float*)d_in[14];
    const float* rho_hid_W = (const float*)d_in[15];
    const float* rho_hid_b = (const float*)d_in[16];
    const float* rho_out_W = (const float*)d_in[17];
    const float* rho_out_b = (const float*)d_in[18];
    const float* rho_proj_W= (const float*)d_in[19];
    const float* rho_proj_b= (const float*)d_in[20];
    const float* c_ll_W[3] = {(const float*)d_in[21], (const float*)d_in[24], (const float*)d_in[27]};
    const float* c_ll_b[3] = {(const float*)d_in[22], (const float*)d_in[25], (const float*)d_in[28]};
    const float* c_lr_W[3] = {(const float*)d_in[23], (const float*)d_in[26], (const float*)d_in[29]};
    const float* h1_in_W   = (const float*)d_in[30];
    const float* h1_in_b   = (const float*)d_in[31];
    const float* h1_hid_W  = (const float*)d_in[32];
    const float* h1_hid_b  = (const float*)d_in[33];
    const float* h1_out_W  = (const float*)d_in[34];
    const float* h1_out_b  = (const float*)d_in[35];
    const float* h1_proj_W = (const float*)d_in[36];
    const float* h1_proj_b = (const float*)d_in[37];
    const float* h2_in_W   = (const float*)d_in[38];
    const float* h2_in_b   = (const float*)d_in[39];
    const float* h2_hid_W  = (const float*)d_in[40];
    const float* h2_hid_b  = (const float*)d_in[41];
    const float* h2_out_W  = (const float*)d_in[42];
    const float* h2_out_b  = (const float*)d_in[43];

    const int N = 50000, Kp = 8, P = 512, E = 1600000, Q = 500000;
    float* out = (float*)d_out;

    // ---- workspace layout ----
    char* wsb = (char*)d_ws;
    size_t off = 0;
    auto ALLOC = [&](size_t bytes) -> char* {
        char* p = wsb + off; off = (off + bytes + 255) & ~(size_t)255; return p;
    };
    US*  WB   = (US*)ALLOC(508032 * 2);
    US*  z0   = (US*)ALLOC((size_t)N * 64 * 2);
    US*  z1   = (US*)ALLOC((size_t)N * 64 * 2);
    US*  Tc   = (US*)ALLOC((size_t)N * 64 * 2);
    US*  aggB = (US*)ALLOC((size_t)N * 64 * 2);
    int* cnt  = (int*)ALLOC((size_t)N * 4);
    int* indp = (int*)ALLOC((size_t)(N + 1) * 4);
    int* curs = (int*)ALLOC((size_t)N * 4);
    int* esrc = (int*)ALLOC((size_t)E * 4);
    UI*  enc  = (UI*)ALLOC(4096 * 4);
    US*  geb  = (US*)ALLOC(4096 * 2);
    char* arena = wsb + off;
    const size_t arenaBytes = (ws_size > off) ? (ws_size - off) : 0;

    // stacked-weight bf16 offsets (elements)
    enum { O_EmW1 = 0, O_EmWh = 131072, O_EmWo = 147456, O_RhoW1 = 212992, O_RhoWh = 344064,
           O_RhoWo = 360448, O_C1l = 368640, O_C1r = 372736, O_C2l = 376832, O_C2r = 380928,
           O_C3l = 385024, O_C3r = 389120, O_H1W1 = 393216, O_H1Wh = 442368, O_H1Wo = 458752,
           O_H2W1 = 475136, O_H2Wh = 491520 };
    const int wOffL[3] = {O_C1l, O_C2l, O_C3l};
    const int wOffR[3] = {O_C1r, O_C2r, O_C3r};

    WPrm pw; int si = 0;
    auto SEG = [&](const float* s, int o, int n) { pw.s[si].src = s; pw.s[si].dst = o; pw.s[si].n = n; ++si; };
    SEG(em_in_W, O_EmW1, 65536);          SEG(em_proj_W, O_EmW1 + 65536, 65536);
    SEG(em_hid_W, O_EmWh, 16384);         SEG(em_out_W, O_EmWo, 65536);
    SEG(rho_in_W, O_RhoW1, 65536);        SEG(rho_proj_W, O_RhoW1 + 65536, 65536);
    SEG(rho_hid_W, O_RhoWh, 16384);       SEG(rho_out_W, O_RhoWo, 8192);
    SEG(c_ll_W[0], O_C1l, 4096);          SEG(c_lr_W[0], O_C1r, 4096);
    SEG(c_ll_W[1], O_C2l, 4096);          SEG(c_lr_W[1], O_C2r, 4096);
    SEG(c_ll_W[2], O_C3l, 4096);          SEG(c_lr_W[2], O_C3r, 4096);
    SEG(h1_in_W, O_H1W1, 24576);          SEG(h1_proj_W, O_H1W1 + 24576, 24576);
    SEG(h1_hid_W, O_H1Wh, 16384);         SEG(h1_out_W, O_H1Wo, 16384);
    SEG(h2_in_W, O_H2W1, 16384);          SEG(h2_hid_W, O_H2Wh, 16384);
    prep_w<<<dim3(20), dim3(256), 0, stream>>>(pw, WB);

    const US* nullB = nullptr;
    const float* nullF = nullptr;

    // ================= Embedder + rho (chunked over nodes) =================
    {
        const size_t perNode = 4096 + 2048 + 1024 + 512 + 256; // bytes per node in arena
        int nc = 10000;
        if (arenaBytes < (size_t)nc * perNode + 4096) {
            nc = (int)(((arenaBytes > 4096) ? arenaBytes - 4096 : 0) / perNode) & ~15;
            if (nc < 16) nc = 16;
        }
        for (int n0 = 0; n0 < N; n0 += nc) {
            const int cn = imin(nc, N - n0);
            const int R = cn * Kp;
            US* G1 = (US*)arena;
            US* Uu = (US*)(arena + (size_t)nc * 4096);
            US* Ss = (US*)(arena + (size_t)nc * (4096 + 2048));
            US* G2 = (US*)(arena + (size_t)nc * (4096 + 2048 + 1024));
            US* RU = (US*)(arena + (size_t)nc * (4096 + 2048 + 1024 + 512));
            // E1: [t1 | s] = [gelu(x@Wi+bi) | x@Wp+bp]
            gemm_k<512,128,1,true,true,false,false,false><<<dim3((R+127)/128, 2), dim3(256), 0, stream>>>(
                (const void*)(x + (size_t)n0 * Kp * P), P, R, WB + O_EmW1, em_in_b, em_proj_b,
                nullB, 0, nullB, 0, G1, 256);
            // E2: U = s + gelu(t1@Wh+bh)
            gemm_k<128,128,1,false,false,false,true,false><<<dim3((R+127)/128, 1), dim3(256), 0, stream>>>(
                (const void*)G1, 256, R, WB + O_EmWh, em_hid_b, nullF, nullB, 0, G1 + 128, 256, Uu, 128);
            // E3: Ssum[node] = sum_k gelu(U@Wo+bo)
            gemm_k<128,128,1,false,false,false,false,true><<<dim3((R+127)/128, 4), dim3(256), 0, stream>>>(
                (const void*)Uu, 128, R, WB + O_EmWo, em_out_b, nullF, nullB, 0, nullB, 0, Ss, 512);
            // E4: rho [r1 | rs]
            gemm_k<512,128,1,true,false,false,false,false><<<dim3((cn+127)/128, 2), dim3(256), 0, stream>>>(
                (const void*)Ss, 512, cn, WB + O_RhoW1, rho_in_b, rho_proj_b, nullB, 0, nullB, 0, G2, 256);
            // E5: RU = rs + gelu(r1@Wh+bh)
            gemm_k<128,128,1,false,false,false,true,false><<<dim3((cn+127)/128, 1), dim3(256), 0, stream>>>(
                (const void*)G2, 256, cn, WB + O_RhoWh, rho_hid_b, nullF, nullB, 0, G2 + 128, 256, RU, 128);
            // E6: z = RU@Wo+bo
            gemm_k<128,64,0,false,false,false,false,false><<<dim3((cn+127)/128, 1), dim3(256), 0, stream>>>(
                (const void*)RU, 128, cn, WB + O_RhoWo, rho_out_b, nullF, nullB, 0, nullB, 0,
                z0 + (size_t)n0 * 64, 64);
        }
    }

    // ================= CSR build =================
    hipMemsetAsync(cnt, 0, (size_t)N * 4, stream);
    count_k<<<dim3((E + 255) / 256), dim3(256), 0, stream>>>(eidx + E, cnt, E);
    scan_csr<<<dim3(1), dim3(1024), 0, stream>>>(cnt, N, indp, curs);
    fill_k<<<dim3((E + 255) / 256), dim3(256), 0, stream>>>(eidx, eidx + E, curs, esrc, E);

    // ================= 3x SAGE residual =================
    US* zin = z0; US* zout = z1;
    for (int ci = 0; ci < 3; ++ci) {
        sage_agg<<<dim3((N + 3) / 4), dim3(256), 0, stream>>>(zin, indp, esrc, aggB, N);
        gemm_k<64,64,0,false,false,false,false,false><<<dim3((N+127)/128, 1), dim3(256), 0, stream>>>(
            (const void*)aggB, 64, N, WB + wOffL[ci], c_ll_b[ci], nullF, nullB, 0, nullB, 0, Tc, 64);
        gemm_k<64,64,1,false,false,true,true,false><<<dim3((N+127)/128, 1), dim3(256), 0, stream>>>(
            (const void*)zin, 64, N, WB + wOffR[ci], nullF, nullF, Tc, 64, zin, 64, zout, 64);
        US* t = zin; zin = zout; zout = t;
    }
    US* zf = zin;

    // ================= graph max-pool =================
    hipMemsetAsync(enc, 0, 4096 * 4, stream);
    segmax_k<<<dim3((N + 511) / 512), dim3(256), 0, stream>>>(zf, batch, enc, N, 128);
    decode_ge<<<dim3(16), dim3(256), 0, stream>>>(enc, geb);

    // node_embeddings output
    copy_bf2f<<<dim3(2048), dim3(256), 0, stream>>>(zf, out, (long)N * 64);

    // ================= heads (chunked over queries) =================
    float* outHead = out + (size_t)N * 64;
    float* outXY   = out + (size_t)N * 64 + 2 * (size_t)Q;
    {
        const size_t perQ = 768 + 512 + 256 + 256;
        int qc = 125000;
        if (arenaBytes < (size_t)qc * perQ + 4096) {
            qc = (int)(((arenaBytes > 4096) ? arenaBytes - 4096 : 0) / perQ) & ~63;
            if (qc < 64) qc = 64;
        }
        for (int q0 = 0; q0 < Q; q0 += qc) {
            const int cq = imin(qc, Q - q0);
            float* yxB = (float*)arena;
            US* QA = (US*)(arena + (size_t)qc * 768);
            US* QU = (US*)(arena + (size_t)qc * (768 + 512));
            US* Tt = (US*)(arena + (size_t)qc * (768 + 512 + 256));
            build_q<<<dim3((cq + 3) / 4), dim3(256), 0, stream>>>(
                srcq + q0, dstq + q0, batch, zf, geb, outXY + (size_t)q0 * 192, yxB, cq);
            for (int side = 0; side < 2; ++side) {
                const float* A0 = side ? yxB : (outXY + (size_t)q0 * 192);
                // Q1: [a1 | s1]
                gemm_k<192,128,1,true,true,false,false,false><<<dim3((cq+127)/128, 2), dim3(256), 0, stream>>>(
                    (const void*)A0, 192, cq, WB + O_H1W1, h1_in_b, h1_proj_b, nullB, 0, nullB, 0, QA, 256);
                // Q2: u = s1 + gelu(a1@Wh+bh)
                gemm_k<128,128,1,false,false,false,true,false><<<dim3((cq+127)/128, 1), dim3(256), 0, stream>>>(
                    (const void*)QA, 256, cq, WB + O_H1Wh, h1_hid_b, nullF, nullB, 0, QA + 128, 256, QU, 128);
                // Q3: t = relu(u@Wo+bo)
                gemm_k<128,128,2,false,false,false,false,false><<<dim3((cq+127)/128, 1), dim3(256), 0, stream>>>(
                    (const void*)QU, 128, cq, WB + O_H1Wo, h1_out_b, nullF, nullB, 0, nullB, 0, Tt, 128);
                // Q4: b1 = gelu(t@W+b)
                gemm_k<128,128,1,false,false,false,false,false><<<dim3((cq+127)/128, 1), dim3(256), 0, stream>>>(
                    (const void*)Tt, 128, cq, WB + O_H2W1, h2_in_b, nullF, nullB, 0, nullB, 0, QA, 128);
                // Q5: u2 = t + gelu(b1@Wh+bh)
                gemm_k<128,128,1,false,false,false,true,false><<<dim3((cq+127)/128, 1), dim3(256), 0, stream>>>(
                    (const void*)QA, 128, cq, WB + O_H2Wh, h2_hid_b, nullF, nullB, 0, Tt, 128, QU, 128);
                // Q6: scalar head
                head_dot<<<dim3((cq + 3) / 4), dim3(256), 0, stream>>>(
                    QU, h2_out_W, h2_out_b, outHead + (size_t)side * Q + q0, cq);
            }
        }
    }
}